// Round 4
// baseline (645.412 us; speedup 1.0000x reference)
//
#include <hip/hip_runtime.h>
#include <hip/hip_bf16.h>

#define NE 32000
#define NNODES 1600
#define CCH 128
#define M0C 7
#define NSPH 49
#define NALLC 29
#define BASIS 512
#define DIN 768
#define HID 128
#define RESCALE_F 23.395238876342773f
#define CH 28                      // edges per rotate staging pass

typedef __bf16 bf16x8 __attribute__((ext_vector_type(8)));
typedef __bf16 bf16x2 __attribute__((ext_vector_type(2)));
typedef float  f32x4  __attribute__((ext_vector_type(4)));

__device__ __forceinline__ unsigned short f_to_bf16(float f) {
    unsigned int u = __float_as_uint(f);
    unsigned int r = (u + 0x7FFFu + ((u >> 16) & 1u)) >> 16;
    return (unsigned short)r;
}
__device__ __forceinline__ float silu_f(float x) {
    return x / (1.0f + __expf(-x));
}

// dot2 over a bf16 pair packed in a dword: c += lo(a)*lo(b) + hi(a)*hi(b)
__device__ __forceinline__ float dot2_bf16(unsigned int a, unsigned int b, float c) {
#if __has_builtin(__builtin_amdgcn_fdot2_f32_bf16)
    union { unsigned int u; bf16x2 h; } ua, ub;
    ua.u = a; ub.u = b;
    return __builtin_amdgcn_fdot2_f32_bf16(ua.h, ub.h, c, false);
#else
    float r = c;
    r = fmaf(__uint_as_float(a << 16), __uint_as_float(b << 16), r);
    r = fmaf(__uint_as_float(a & 0xFFFF0000u), __uint_as_float(b & 0xFFFF0000u), r);
    return r;
#endif
}

// ---------------- prepack weights: FRAGMENT-LINEAR layout.
// B-fragment for (kstep, tile) is 512 bf16 = 1 KB, stored so that lane L's 8
// values sit at [lane*8 .. lane*8+8). A wave's B load is then ONE contiguous
// 1 KB fetch (previously: 16 separate 64B lines per load instruction).
//   lane = quad*16 + m ; source element = w[k][n], k = kstep*32+quad*8+j,
//   w1p: n = ct*16+m         (24 ksteps x 8 ct)
//   w2p: n = ct*16+m         ( 4 ksteps x 8 ct)
//   w3p: n = o*128+ctile*16+m ( 4 ksteps x 7 o x 8 ctile)
__global__ __launch_bounds__(256) void prepack_w(
    const float* __restrict__ w1, const float* __restrict__ w2, const float* __restrict__ w3,
    unsigned short* __restrict__ w1p,  // [24][8][512]
    unsigned short* __restrict__ w2p,  // [4][8][512]
    unsigned short* __restrict__ w3p)  // [4][7][8][512]
{
    int idx = blockIdx.x * 256 + threadIdx.x;
    if (idx < 98304) {                       // w1p: 24*8*512
        int kstep = idx >> 12;
        int ct    = (idx >> 9) & 7;
        int li    = idx & 511;
        int lane = li >> 3, j = li & 7;
        int m = lane & 15, quad = lane >> 4;
        int k = kstep * 32 + quad * 8 + j;
        int n = ct * 16 + m;
        w1p[idx] = f_to_bf16(w1[(size_t)k * 128 + n]);
    } else if (idx < 114688) {               // w2p: 4*8*512
        int j2 = idx - 98304;
        int kstep = j2 >> 12;
        int ct    = (j2 >> 9) & 7;
        int li    = j2 & 511;
        int lane = li >> 3, j = li & 7;
        int m = lane & 15, quad = lane >> 4;
        int k = kstep * 32 + quad * 8 + j;
        int n = ct * 16 + m;
        w2p[j2] = f_to_bf16(w2[(size_t)k * 128 + n]);
    } else if (idx < 229376) {               // w3p: 4*7*8*512
        int j3 = idx - 114688;
        int kstep = j3 / 28672;
        int r     = j3 - kstep * 28672;
        int o     = r >> 12;
        int ctile = (r >> 9) & 7;
        int li    = r & 511;
        int lane = li >> 3, j = li & 7;
        int m = lane & 15, quad = lane >> 4;
        int k = kstep * 32 + quad * 8 + j;
        int n = o * 128 + ctile * 16 + m;
        w3p[j3] = f_to_bf16(w3[(size_t)k * 896 + n]);
    }
}

// ---------------- GEMM1 fused: A = [dist|src|tgt] fp32 loaded direct, cvt in-reg.
// 64 rows/block, 4 waves x 16 rows, MFMA 16x16x32 bf16, LN+SiLU epilogue.
__global__ __launch_bounds__(256) void gemm1_ln_mfma(
    const float* __restrict__ dist,         // [NE,512]
    const int* __restrict__ edge_index,     // [2,NE]
    const int* __restrict__ atomic_numbers, // [NNODES]
    const float* __restrict__ src_table,    // [90,128]
    const float* __restrict__ tgt_table,    // [90,128]
    const unsigned short* __restrict__ w1p, // [24][8][512] fragment-linear
    const float* __restrict__ bias,
    const float* __restrict__ gam,
    const float* __restrict__ bet,
    unsigned short* __restrict__ Out)       // [NE,128] bf16
{
    const int t = threadIdx.x;
    const int wv = t >> 6, lane = t & 63;
    const int m = lane & 15, quad = lane >> 4;
    const int row0 = blockIdx.x * 64 + wv * 16;
    const int row = row0 + m;

    const int sid  = atomic_numbers[edge_index[row]];
    const int tid2 = atomic_numbers[edge_index[NE + row]];
    const float* a0 = dist + (size_t)row * 512 + quad * 8;
    const float* a1 = src_table + sid * 128 + quad * 8;
    const float* a2 = tgt_table + tid2 * 128 + quad * 8;
    const unsigned short* bb = w1p + lane * 8;

    f32x4 acc[8] = {};

#pragma unroll
    for (int k0 = 0; k0 < 768; k0 += 32) {
        const float* ap = (k0 < 512) ? (a0 + k0)
                        : (k0 < 640) ? (a1 + (k0 - 512))
                                     : (a2 + (k0 - 640));
        float4 va = *(const float4*)ap;
        float4 vb = *(const float4*)(ap + 4);
        bf16x8 af;
        af[0] = (__bf16)va.x; af[1] = (__bf16)va.y;
        af[2] = (__bf16)va.z; af[3] = (__bf16)va.w;
        af[4] = (__bf16)vb.x; af[5] = (__bf16)vb.y;
        af[6] = (__bf16)vb.z; af[7] = (__bf16)vb.w;
#pragma unroll
        for (int ct = 0; ct < 8; ++ct) {
            bf16x8 bfv = *(const bf16x8*)(bb + (size_t)(((k0 >> 5) * 8 + ct)) * 512);
            acc[ct] = __builtin_amdgcn_mfma_f32_16x16x32_bf16(af, bfv, acc[ct], 0, 0, 0);
        }
    }

    float bbv[8], ggv[8], eev[8];
#pragma unroll
    for (int ct = 0; ct < 8; ++ct) {
        bbv[ct] = bias[ct * 16 + m];
        ggv[ct] = gam[ct * 16 + m];
        eev[ct] = bet[ct * 16 + m];
    }
#pragma unroll
    for (int reg = 0; reg < 4; ++reg) {
        float v[8];
        float s = 0.f, s2 = 0.f;
#pragma unroll
        for (int ct = 0; ct < 8; ++ct) {
            v[ct] = acc[ct][reg] + bbv[ct];
            s += v[ct]; s2 += v[ct] * v[ct];
        }
#pragma unroll
        for (int off = 1; off < 16; off <<= 1) {
            s  += __shfl_xor(s, off, 64);
            s2 += __shfl_xor(s2, off, 64);
        }
        float mean = s * (1.0f / 128.0f);
        float var  = s2 * (1.0f / 128.0f) - mean * mean;
        float rstd = rsqrtf(var + 1e-5f);
        int orow = row0 + 4 * quad + reg;
#pragma unroll
        for (int ct = 0; ct < 8; ++ct) {
            float o = silu_f((v[ct] - mean) * rstd * ggv[ct] + eev[ct]);
            Out[(size_t)orow * 128 + ct * 16 + m] = f_to_bf16(o);
        }
    }
}

// ---------------- GEMM2 (K=128): bf16 A, LN+SiLU -> bf16
__global__ __launch_bounds__(256) void gemm2_ln_mfma(
    const unsigned short* __restrict__ A,
    const unsigned short* __restrict__ w2p,  // [4][8][512] fragment-linear
    const float* __restrict__ bias,
    const float* __restrict__ gam,
    const float* __restrict__ bet,
    unsigned short* __restrict__ Out)
{
    const int t = threadIdx.x;
    const int wv = t >> 6, lane = t & 63;
    const int m = lane & 15, quad = lane >> 4;
    const int row0 = blockIdx.x * 64 + wv * 16;

    f32x4 acc[8] = {};
    const unsigned short* arow = A + (size_t)(row0 + m) * 128 + quad * 8;
    const unsigned short* bb   = w2p + lane * 8;

#pragma unroll
    for (int k0 = 0; k0 < 128; k0 += 32) {
        bf16x8 af = *(const bf16x8*)(arow + k0);
#pragma unroll
        for (int ct = 0; ct < 8; ++ct) {
            bf16x8 bfv = *(const bf16x8*)(bb + (size_t)(((k0 >> 5) * 8 + ct)) * 512);
            acc[ct] = __builtin_amdgcn_mfma_f32_16x16x32_bf16(af, bfv, acc[ct], 0, 0, 0);
        }
    }

    float bbv[8], ggv[8], eev[8];
#pragma unroll
    for (int ct = 0; ct < 8; ++ct) {
        bbv[ct] = bias[ct * 16 + m];
        ggv[ct] = gam[ct * 16 + m];
        eev[ct] = bet[ct * 16 + m];
    }
#pragma unroll
    for (int reg = 0; reg < 4; ++reg) {
        float v[8];
        float s = 0.f, s2 = 0.f;
#pragma unroll
        for (int ct = 0; ct < 8; ++ct) {
            v[ct] = acc[ct][reg] + bbv[ct];
            s += v[ct]; s2 += v[ct] * v[ct];
        }
#pragma unroll
        for (int off = 1; off < 16; off <<= 1) {
            s  += __shfl_xor(s, off, 64);
            s2 += __shfl_xor(s2, off, 64);
        }
        float mean = s * (1.0f / 128.0f);
        float var  = s2 * (1.0f / 128.0f) - mean * mean;
        float rstd = rsqrtf(var + 1e-5f);
        int row = row0 + 4 * quad + reg;
#pragma unroll
        for (int ct = 0; ct < 8; ++ct) {
            float o = silu_f((v[ct] - mean) * rstd * ggv[ct] + eev[ct]);
            Out[(size_t)row * 128 + ct * 16 + m] = f_to_bf16(o);
        }
    }
}

// ---------------- GEMM3: H2b @ w3 + b3, /RESCALE -> bf16 X0p [NE,128,8]
// One block = 16 edge rows, 4 waves; wave w owns c-range [w*32, w*32+32) and
// ALL 7 o-values (14 MFMA tiles). Each thread packs the o-minor bf16x8 word
// per (row,c) and emits ONE aligned 16B store (fully coalesced).
__global__ __launch_bounds__(256) void gemm3_mfma(
    const unsigned short* __restrict__ A,    // [NE,128]
    const unsigned short* __restrict__ w3p,  // [4][7][8][512] fragment-linear
    const float* __restrict__ b3,            // [896]
    unsigned short* __restrict__ X0p)        // [NE,128,8]
{
    const int t = threadIdx.x;
    const int wv = t >> 6, lane = t & 63;
    const int m = lane & 15, quad = lane >> 4;
    const int row0 = blockIdx.x * 16;
    const int c0 = wv * 32;

    f32x4 acc[14] = {};   // index = o*2 + chalf
    const unsigned short* arow = A + (size_t)(row0 + m) * 128 + quad * 8;
    const unsigned short* bb   = w3p + lane * 8;

#pragma unroll
    for (int k0 = 0; k0 < 128; k0 += 32) {
        bf16x8 af = *(const bf16x8*)(arow + k0);
#pragma unroll
        for (int o = 0; o < 7; ++o) {
#pragma unroll
            for (int ch2 = 0; ch2 < 2; ++ch2) {
                bf16x8 bfv = *(const bf16x8*)(bb +
                    (size_t)((((k0 >> 5) * 7 + o) * 8 + (wv * 2 + ch2))) * 512);
                acc[o * 2 + ch2] =
                    __builtin_amdgcn_mfma_f32_16x16x32_bf16(af, bfv, acc[o * 2 + ch2], 0, 0, 0);
            }
        }
    }

    const float inv_res = 1.0f / RESCALE_F;
    float bv[14];
#pragma unroll
    for (int o = 0; o < 7; ++o)
#pragma unroll
        for (int ch2 = 0; ch2 < 2; ++ch2)
            bv[o * 2 + ch2] = b3[o * 128 + c0 + ch2 * 16 + m];

#pragma unroll
    for (int reg = 0; reg < 4; ++reg) {
        int row = row0 + 4 * quad + reg;
#pragma unroll
        for (int ch2 = 0; ch2 < 2; ++ch2) {
            int c = c0 + ch2 * 16 + m;
            union { unsigned short us[8]; uint4 q; } pk;
#pragma unroll
            for (int o = 0; o < 7; ++o)
                pk.us[o] = f_to_bf16((acc[o * 2 + ch2][reg] + bv[o * 2 + ch2]) * inv_res);
            pk.us[7] = 0;   // zero pad (the dot2 partner of any Ws pad garbage must be 0)
            *(uint4*)(X0p + (size_t)row * 1024 + c * 8) = pk.q;
        }
    }
}

// ---------------- counting sort of edges by target node
__global__ __launch_bounds__(256) void hist_kernel(
    const int* __restrict__ edge_index, int* __restrict__ cnt)
{
    int e = blockIdx.x * 256 + threadIdx.x;
    if (e < NE) atomicAdd(&cnt[edge_index[NE + e]], 1);
}

__global__ __launch_bounds__(256) void scan_kernel(
    const int* __restrict__ cnt, int* __restrict__ offs, int* __restrict__ cur)
{
    __shared__ int part[256];
    const int t = threadIdx.x;
    const int base = t * 7;
    int s = 0;
#pragma unroll
    for (int j = 0; j < 7; ++j) {
        int i = base + j;
        if (i < NNODES) s += cnt[i];
    }
    part[t] = s;
    __syncthreads();
    for (int off = 1; off < 256; off <<= 1) {
        int v = (t >= off) ? part[t - off] : 0;
        __syncthreads();
        part[t] += v;
        __syncthreads();
    }
    int run = (t > 0) ? part[t - 1] : 0;
#pragma unroll
    for (int j = 0; j < 7; ++j) {
        int i = base + j;
        if (i < NNODES) {
            offs[i] = run;
            cur[i] = run;
            run += cnt[i];
        }
    }
    if (t == 0) offs[NNODES] = part[255];
}

__global__ __launch_bounds__(256) void scatter_kernel(
    const int* __restrict__ edge_index, int* __restrict__ cur, int* __restrict__ order)
{
    int e = blockIdx.x * 256 + threadIdx.x;
    if (e < NE) {
        int tgt = edge_index[NE + e];
        int pos = atomicAdd(&cur[tgt], 1);
        order[pos] = e;
    }
}

// ---------------- rotate + reduce: ONE BLOCK PER NODE, looping over <=CH-edge
// staging passes. No chunk list, no output atomics, no d_out memset (zero-edge
// nodes store zeros). Wigner staging: each wave loads an edge's FULL 49x29 f32
// block with lane-linear coalesced dword loads and extracts the 7 needed
// columns in-register (idx/29, idx%29, membership) -> masked ds_write.
__global__ __launch_bounds__(256) void rotate_nodes(
    const unsigned short* __restrict__ X0p, // [NE,128,8] bf16 (already /RESCALE)
    const float* __restrict__ wig,          // [NE,49,29]
    const int* __restrict__ order,
    const int* __restrict__ offs,           // [NNODES+1]
    float* __restrict__ out)                // [1600,49,128]
{
    __shared__ unsigned short Ws[CH][NSPH][8];  // [slot][row][o(7)+pad] 21952 B
    __shared__ int es[CH];

    const int node = blockIdx.x;
    const int beg = offs[node], end = offs[node + 1];

    const int t = threadIdx.x;
    const int wv = t >> 6, lane = t & 63;
    const int cg = t & 31;   // cols 4*cg .. 4*cg+3
    const int rg = t >> 5;   // rows rg + 8r

    float acc[7][4];
#pragma unroll
    for (int r = 0; r < 7; ++r)
#pragma unroll
        for (int j = 0; j < 4; ++j) acc[r][j] = 0.0f;

    for (int base = beg; base < end; base += CH) {
        const int cnt = min(CH, end - base);
        __syncthreads();   // guard Ws/es reuse against previous pass's compute
        if (t < CH) es[t] = order[base + ((t < cnt) ? t : 0)];

        // ---- stage: wave wv handles slots wv, wv+4, ...
        for (int s = wv; s < cnt; s += 4) {
            const int e = order[base + s];          // wave-uniform scalar load
            const float* wsrc = wig + (size_t)e * (NSPH * NALLC);
            if (lane < NSPH) Ws[s][lane][7] = 0;    // zero pad (NaN guard)
#pragma unroll
            for (int it = 0; it < 23; ++it) {
                int idx = it * 64 + lane;           // 0..1471 (1421 valid)
                if (idx < NSPH * NALLC) {
                    float v = wsrc[idx];            // fully coalesced
                    int i = idx / 29;
                    int c = idx - i * 29;
                    int o = -1;
                    if (c == 0) o = 0;
                    else if (c == 2) o = 1;
                    else if (c >= 6) {
                        int d = c - 6, q = d / 5;
                        if (d - q * 5 == 0) o = q + 2;   // c in {6,11,16,21,26}
                    }
                    if (o >= 0) Ws[s][i][o] = f_to_bf16(v);
                }
            }
        }
        __syncthreads();

        // ---- compute: one-edge-ahead X prefetch pipeline
        uint4 xq0, xq1, xq2, xq3;
        {
            const uint4* xp = (const uint4*)(X0p + (size_t)es[0] * 1024 + 32 * cg);
            xq0 = xp[0]; xq1 = xp[1]; xq2 = xp[2]; xq3 = xp[3];
        }
        for (int s = 0; s < cnt; ++s) {
            int snx = (s + 1 < cnt) ? (s + 1) : s;
            const uint4* xp = (const uint4*)(X0p + (size_t)es[snx] * 1024 + 32 * cg);
            uint4 xn0 = xp[0], xn1 = xp[1], xn2 = xp[2], xn3 = xp[3];

#pragma unroll
            for (int r = 0; r < 7; ++r) {
                int row = rg + 8 * r;
                if (row < NSPH) {
                    uint4 wq = *(const uint4*)&Ws[s][row][0];
                    float a0 = acc[r][0], a1 = acc[r][1], a2 = acc[r][2], a3 = acc[r][3];
                    a0 = dot2_bf16(xq0.x, wq.x, a0);
                    a0 = dot2_bf16(xq0.y, wq.y, a0);
                    a0 = dot2_bf16(xq0.z, wq.z, a0);
                    a0 = dot2_bf16(xq0.w, wq.w, a0);
                    a1 = dot2_bf16(xq1.x, wq.x, a1);
                    a1 = dot2_bf16(xq1.y, wq.y, a1);
                    a1 = dot2_bf16(xq1.z, wq.z, a1);
                    a1 = dot2_bf16(xq1.w, wq.w, a1);
                    a2 = dot2_bf16(xq2.x, wq.x, a2);
                    a2 = dot2_bf16(xq2.y, wq.y, a2);
                    a2 = dot2_bf16(xq2.z, wq.z, a2);
                    a2 = dot2_bf16(xq2.w, wq.w, a2);
                    a3 = dot2_bf16(xq3.x, wq.x, a3);
                    a3 = dot2_bf16(xq3.y, wq.y, a3);
                    a3 = dot2_bf16(xq3.z, wq.z, a3);
                    a3 = dot2_bf16(xq3.w, wq.w, a3);
                    acc[r][0] = a0; acc[r][1] = a1; acc[r][2] = a2; acc[r][3] = a3;
                }
            }
            xq0 = xn0; xq1 = xn1; xq2 = xn2; xq3 = xn3;
        }
    }

    // ---- store: plain coalesced float4 (covers zero-edge nodes with zeros)
    float* op = out + (size_t)node * (NSPH * CCH);
#pragma unroll
    for (int r = 0; r < 7; ++r) {
        int row = rg + 8 * r;
        if (row < NSPH) {
            *(float4*)&op[row * CCH + 4 * cg] =
                make_float4(acc[r][0], acc[r][1], acc[r][2], acc[r][3]);
        }
    }
}

extern "C" void kernel_launch(void* const* d_in, const int* in_sizes, int n_in,
                              void* d_out, int out_size, void* d_ws, size_t ws_size,
                              hipStream_t stream) {
    const int*   atomic_numbers = (const int*)d_in[0];
    const float* edge_distance  = (const float*)d_in[1];
    const int*   edge_index     = (const int*)d_in[2];
    const float* src_table      = (const float*)d_in[3];
    const float* tgt_table      = (const float*)d_in[4];
    const float* w1  = (const float*)d_in[5];
    const float* b1  = (const float*)d_in[6];
    const float* g1  = (const float*)d_in[7];
    const float* be1 = (const float*)d_in[8];
    const float* w2  = (const float*)d_in[9];
    const float* b2  = (const float*)d_in[10];
    const float* g2  = (const float*)d_in[11];
    const float* be2 = (const float*)d_in[12];
    const float* w3  = (const float*)d_in[13];
    const float* b3  = (const float*)d_in[14];
    // d_in[15] = to_m (fixed permutation, hard-coded)
    const float* wig = (const float*)d_in[16];

    char* ws = (char*)d_ws;
    // Non-overlapping layout, total ~82.5 MB (ws >= 90.1 MB proven previously)
    unsigned short* H1b = (unsigned short*)(ws);                 //  8.192 MB
    unsigned short* H2b = (unsigned short*)(ws + 8192000);       //  8.192 MB
    unsigned short* X0p = (unsigned short*)(ws + 16384000);      // 65.536 MB [NE,128,8]
    unsigned short* w1p = (unsigned short*)(ws + 81920000);      // 196608 B
    unsigned short* w2p = (unsigned short*)(ws + 82116608);      // 32768 B
    unsigned short* w3p = (unsigned short*)(ws + 82149376);      // 229376 B
    int* ints      = (int*)(ws + 82378752);
    int* cnt       = ints;                   // [1600]
    int* offs      = cnt + NNODES;           // [1601]
    int* cur       = offs + NNODES + 1;      // [1600]
    int* order     = cur + NNODES;           // [32000]

    // zero the histogram counters (output no longer needs pre-zeroing:
    // rotate_nodes fully writes every node, including empty ones)
    hipMemsetAsync(cnt, 0, NNODES * sizeof(int), stream);

    // bucket by target node
    hist_kernel<<<(NE + 255) / 256, 256, 0, stream>>>(edge_index, cnt);
    scan_kernel<<<1, 256, 0, stream>>>(cnt, offs, cur);
    scatter_kernel<<<(NE + 255) / 256, 256, 0, stream>>>(edge_index, cur, order);

    // weights prepack + MLP (bf16 MFMA)
    prepack_w<<<(229376 + 255) / 256, 256, 0, stream>>>(w1, w2, w3, w1p, w2p, w3p);
    gemm1_ln_mfma<<<NE / 64, 256, 0, stream>>>(
        edge_distance, edge_index, atomic_numbers, src_table, tgt_table,
        w1p, b1, g1, be1, H1b);
    gemm2_ln_mfma<<<NE / 64, 256, 0, stream>>>(H1b, w2p, b2, g2, be2, H2b);
    gemm3_mfma<<<NE / 16, 256, 0, stream>>>(H2b, w3p, b3, X0p);

    // rotate + reduce: one block per node
    rotate_nodes<<<NNODES, 256, 0, stream>>>(X0p, wig, order, offs, (float*)d_out);
}

// Round 5
// 453.618 us; speedup vs baseline: 1.4228x; 1.4228x over previous
//
#include <hip/hip_runtime.h>
#include <hip/hip_bf16.h>

#define NE 32000
#define NNODES 1600
#define CCH 128
#define M0C 7
#define NSPH 49
#define NALLC 29
#define BASIS 512
#define DIN 768
#define HID 128
#define RESCALE_F 23.395238876342773f
#define CH 28                      // edges per rotate chunk
#define MAXCH (NE / CH + NNODES)   // 2743 upper bound on chunk count

typedef __bf16 bf16x8 __attribute__((ext_vector_type(8)));
typedef __bf16 bf16x2 __attribute__((ext_vector_type(2)));
typedef float  f32x4  __attribute__((ext_vector_type(4)));

__device__ __forceinline__ unsigned short f_to_bf16(float f) {
    unsigned int u = __float_as_uint(f);
    unsigned int r = (u + 0x7FFFu + ((u >> 16) & 1u)) >> 16;
    return (unsigned short)r;
}
__device__ __forceinline__ float silu_f(float x) {
    return x / (1.0f + __expf(-x));
}

// ---------------- prepack weights: FRAGMENT-LINEAR layout.
// B-fragment for (kstep, tile) is 512 bf16 = 1 KB, stored so that lane L's 8
// values sit at [lane*8 .. lane*8+8). A wave's B load is then ONE contiguous
// 1 KB fetch.
__global__ __launch_bounds__(256) void prepack_w(
    const float* __restrict__ w1, const float* __restrict__ w2, const float* __restrict__ w3,
    unsigned short* __restrict__ w1p,  // [24][8][512]
    unsigned short* __restrict__ w2p,  // [4][8][512]
    unsigned short* __restrict__ w3p)  // [4][7][8][512]
{
    int idx = blockIdx.x * 256 + threadIdx.x;
    if (idx < 98304) {                       // w1p: 24*8*512
        int kstep = idx >> 12;
        int ct    = (idx >> 9) & 7;
        int li    = idx & 511;
        int lane = li >> 3, j = li & 7;
        int m = lane & 15, quad = lane >> 4;
        int k = kstep * 32 + quad * 8 + j;
        int n = ct * 16 + m;
        w1p[idx] = f_to_bf16(w1[(size_t)k * 128 + n]);
    } else if (idx < 114688) {               // w2p: 4*8*512
        int j2 = idx - 98304;
        int kstep = j2 >> 12;
        int ct    = (j2 >> 9) & 7;
        int li    = j2 & 511;
        int lane = li >> 3, j = li & 7;
        int m = lane & 15, quad = lane >> 4;
        int k = kstep * 32 + quad * 8 + j;
        int n = ct * 16 + m;
        w2p[j2] = f_to_bf16(w2[(size_t)k * 128 + n]);
    } else if (idx < 229376) {               // w3p: 4*7*8*512
        int j3 = idx - 114688;
        int kstep = j3 / 28672;
        int r     = j3 - kstep * 28672;
        int o     = r >> 12;
        int ctile = (r >> 9) & 7;
        int li    = r & 511;
        int lane = li >> 3, j = li & 7;
        int m = lane & 15, quad = lane >> 4;
        int k = kstep * 32 + quad * 8 + j;
        int n = o * 128 + ctile * 16 + m;
        w3p[j3] = f_to_bf16(w3[(size_t)k * 896 + n]);
    }
}

// ---------------- GEMM1 fused: A = [dist|src|tgt] fp32 loaded direct, cvt in-reg.
__global__ __launch_bounds__(256) void gemm1_ln_mfma(
    const float* __restrict__ dist,         // [NE,512]
    const int* __restrict__ edge_index,     // [2,NE]
    const int* __restrict__ atomic_numbers, // [NNODES]
    const float* __restrict__ src_table,    // [90,128]
    const float* __restrict__ tgt_table,    // [90,128]
    const unsigned short* __restrict__ w1p, // [24][8][512] fragment-linear
    const float* __restrict__ bias,
    const float* __restrict__ gam,
    const float* __restrict__ bet,
    unsigned short* __restrict__ Out)       // [NE,128] bf16
{
    const int t = threadIdx.x;
    const int wv = t >> 6, lane = t & 63;
    const int m = lane & 15, quad = lane >> 4;
    const int row0 = blockIdx.x * 64 + wv * 16;
    const int row = row0 + m;

    const int sid  = atomic_numbers[edge_index[row]];
    const int tid2 = atomic_numbers[edge_index[NE + row]];
    const float* a0 = dist + (size_t)row * 512 + quad * 8;
    const float* a1 = src_table + sid * 128 + quad * 8;
    const float* a2 = tgt_table + tid2 * 128 + quad * 8;
    const unsigned short* bb = w1p + lane * 8;

    f32x4 acc[8] = {};

#pragma unroll
    for (int k0 = 0; k0 < 768; k0 += 32) {
        const float* ap = (k0 < 512) ? (a0 + k0)
                        : (k0 < 640) ? (a1 + (k0 - 512))
                                     : (a2 + (k0 - 640));
        float4 va = *(const float4*)ap;
        float4 vb = *(const float4*)(ap + 4);
        bf16x8 af;
        af[0] = (__bf16)va.x; af[1] = (__bf16)va.y;
        af[2] = (__bf16)va.z; af[3] = (__bf16)va.w;
        af[4] = (__bf16)vb.x; af[5] = (__bf16)vb.y;
        af[6] = (__bf16)vb.z; af[7] = (__bf16)vb.w;
#pragma unroll
        for (int ct = 0; ct < 8; ++ct) {
            bf16x8 bfv = *(const bf16x8*)(bb + (size_t)(((k0 >> 5) * 8 + ct)) * 512);
            acc[ct] = __builtin_amdgcn_mfma_f32_16x16x32_bf16(af, bfv, acc[ct], 0, 0, 0);
        }
    }

    float bbv[8], ggv[8], eev[8];
#pragma unroll
    for (int ct = 0; ct < 8; ++ct) {
        bbv[ct] = bias[ct * 16 + m];
        ggv[ct] = gam[ct * 16 + m];
        eev[ct] = bet[ct * 16 + m];
    }
#pragma unroll
    for (int reg = 0; reg < 4; ++reg) {
        float v[8];
        float s = 0.f, s2 = 0.f;
#pragma unroll
        for (int ct = 0; ct < 8; ++ct) {
            v[ct] = acc[ct][reg] + bbv[ct];
            s += v[ct]; s2 += v[ct] * v[ct];
        }
#pragma unroll
        for (int off = 1; off < 16; off <<= 1) {
            s  += __shfl_xor(s, off, 64);
            s2 += __shfl_xor(s2, off, 64);
        }
        float mean = s * (1.0f / 128.0f);
        float var  = s2 * (1.0f / 128.0f) - mean * mean;
        float rstd = rsqrtf(var + 1e-5f);
        int orow = row0 + 4 * quad + reg;
#pragma unroll
        for (int ct = 0; ct < 8; ++ct) {
            float o = silu_f((v[ct] - mean) * rstd * ggv[ct] + eev[ct]);
            Out[(size_t)orow * 128 + ct * 16 + m] = f_to_bf16(o);
        }
    }
}

// ---------------- GEMM2 (K=128): bf16 A, LN+SiLU -> bf16
__global__ __launch_bounds__(256) void gemm2_ln_mfma(
    const unsigned short* __restrict__ A,
    const unsigned short* __restrict__ w2p,  // [4][8][512] fragment-linear
    const float* __restrict__ bias,
    const float* __restrict__ gam,
    const float* __restrict__ bet,
    unsigned short* __restrict__ Out)
{
    const int t = threadIdx.x;
    const int wv = t >> 6, lane = t & 63;
    const int m = lane & 15, quad = lane >> 4;
    const int row0 = blockIdx.x * 64 + wv * 16;

    f32x4 acc[8] = {};
    const unsigned short* arow = A + (size_t)(row0 + m) * 128 + quad * 8;
    const unsigned short* bb   = w2p + lane * 8;

#pragma unroll
    for (int k0 = 0; k0 < 128; k0 += 32) {
        bf16x8 af = *(const bf16x8*)(arow + k0);
#pragma unroll
        for (int ct = 0; ct < 8; ++ct) {
            bf16x8 bfv = *(const bf16x8*)(bb + (size_t)(((k0 >> 5) * 8 + ct)) * 512);
            acc[ct] = __builtin_amdgcn_mfma_f32_16x16x32_bf16(af, bfv, acc[ct], 0, 0, 0);
        }
    }

    float bbv[8], ggv[8], eev[8];
#pragma unroll
    for (int ct = 0; ct < 8; ++ct) {
        bbv[ct] = bias[ct * 16 + m];
        ggv[ct] = gam[ct * 16 + m];
        eev[ct] = bet[ct * 16 + m];
    }
#pragma unroll
    for (int reg = 0; reg < 4; ++reg) {
        float v[8];
        float s = 0.f, s2 = 0.f;
#pragma unroll
        for (int ct = 0; ct < 8; ++ct) {
            v[ct] = acc[ct][reg] + bbv[ct];
            s += v[ct]; s2 += v[ct] * v[ct];
        }
#pragma unroll
        for (int off = 1; off < 16; off <<= 1) {
            s  += __shfl_xor(s, off, 64);
            s2 += __shfl_xor(s2, off, 64);
        }
        float mean = s * (1.0f / 128.0f);
        float var  = s2 * (1.0f / 128.0f) - mean * mean;
        float rstd = rsqrtf(var + 1e-5f);
        int row = row0 + 4 * quad + reg;
#pragma unroll
        for (int ct = 0; ct < 8; ++ct) {
            float o = silu_f((v[ct] - mean) * rstd * ggv[ct] + eev[ct]);
            Out[(size_t)row * 128 + ct * 16 + m] = f_to_bf16(o);
        }
    }
}

// ---------------- GEMM3: H2b @ w3 + b3, /RESCALE -> bf16 X0p [NE,128,8]
// o-minor padded layout; each thread packs a full o-column bf16x8 word and
// emits ONE aligned 16B store (fully coalesced).
__global__ __launch_bounds__(256) void gemm3_mfma(
    const unsigned short* __restrict__ A,    // [NE,128]
    const unsigned short* __restrict__ w3p,  // [4][7][8][512] fragment-linear
    const float* __restrict__ b3,            // [896]
    unsigned short* __restrict__ X0p)        // [NE,128,8]
{
    const int t = threadIdx.x;
    const int wv = t >> 6, lane = t & 63;
    const int m = lane & 15, quad = lane >> 4;
    const int row0 = blockIdx.x * 16;
    const int c0 = wv * 32;

    f32x4 acc[14] = {};   // index = o*2 + chalf
    const unsigned short* arow = A + (size_t)(row0 + m) * 128 + quad * 8;
    const unsigned short* bb   = w3p + lane * 8;

#pragma unroll
    for (int k0 = 0; k0 < 128; k0 += 32) {
        bf16x8 af = *(const bf16x8*)(arow + k0);
#pragma unroll
        for (int o = 0; o < 7; ++o) {
#pragma unroll
            for (int ch2 = 0; ch2 < 2; ++ch2) {
                bf16x8 bfv = *(const bf16x8*)(bb +
                    (size_t)((((k0 >> 5) * 7 + o) * 8 + (wv * 2 + ch2))) * 512);
                acc[o * 2 + ch2] =
                    __builtin_amdgcn_mfma_f32_16x16x32_bf16(af, bfv, acc[o * 2 + ch2], 0, 0, 0);
            }
        }
    }

    const float inv_res = 1.0f / RESCALE_F;
    float bv[14];
#pragma unroll
    for (int o = 0; o < 7; ++o)
#pragma unroll
        for (int ch2 = 0; ch2 < 2; ++ch2)
            bv[o * 2 + ch2] = b3[o * 128 + c0 + ch2 * 16 + m];

#pragma unroll
    for (int reg = 0; reg < 4; ++reg) {
        int row = row0 + 4 * quad + reg;
#pragma unroll
        for (int ch2 = 0; ch2 < 2; ++ch2) {
            int c = c0 + ch2 * 16 + m;
            union { unsigned short us[8]; uint4 q; } pk;
#pragma unroll
            for (int o = 0; o < 7; ++o)
                pk.us[o] = f_to_bf16((acc[o * 2 + ch2][reg] + bv[o * 2 + ch2]) * inv_res);
            pk.us[7] = 0;   // zero pad: K-pad lane of the rotate MFMA must be 0
            *(uint4*)(X0p + (size_t)row * 1024 + c * 8) = pk.q;
        }
    }
}

// ---------------- counting sort of edges by target node
__global__ __launch_bounds__(256) void hist_kernel(
    const int* __restrict__ edge_index, int* __restrict__ cnt)
{
    int e = blockIdx.x * 256 + threadIdx.x;
    if (e < NE) atomicAdd(&cnt[edge_index[NE + e]], 1);
}

__global__ __launch_bounds__(256) void scan_kernel(
    const int* __restrict__ cnt, int* __restrict__ offs, int* __restrict__ cur)
{
    __shared__ int part[256];
    const int t = threadIdx.x;
    const int base = t * 7;
    int s = 0;
#pragma unroll
    for (int j = 0; j < 7; ++j) {
        int i = base + j;
        if (i < NNODES) s += cnt[i];
    }
    part[t] = s;
    __syncthreads();
    for (int off = 1; off < 256; off <<= 1) {
        int v = (t >= off) ? part[t - off] : 0;
        __syncthreads();
        part[t] += v;
        __syncthreads();
    }
    int run = (t > 0) ? part[t - 1] : 0;
#pragma unroll
    for (int j = 0; j < 7; ++j) {
        int i = base + j;
        if (i < NNODES) {
            offs[i] = run;
            cur[i] = run;
            run += cnt[i];
        }
    }
    if (t == 0) offs[NNODES] = part[255];
}

__global__ __launch_bounds__(256) void scatter_kernel(
    const int* __restrict__ edge_index, int* __restrict__ cur, int* __restrict__ order)
{
    int e = blockIdx.x * 256 + threadIdx.x;
    if (e < NE) {
        int tgt = edge_index[NE + e];
        int pos = atomicAdd(&cur[tgt], 1);
        order[pos] = e;
    }
}

// ---------------- chunk list: one node per chunk, <=CH edges; multi-chunk nodes atomic
__global__ __launch_bounds__(256) void build_chunks(
    const int* __restrict__ offs, int* __restrict__ chunk_cnt,
    int* __restrict__ ch_node, int* __restrict__ ch_beg, int* __restrict__ ch_lm)
{
    int n = blockIdx.x * 256 + threadIdx.x;
    if (n >= NNODES) return;
    int b = offs[n], k = offs[n + 1] - b;
    if (k == 0) return;
    int nc = (k + CH - 1) / CH;
    int base = atomicAdd(chunk_cnt, nc);
    for (int c = 0; c < nc; ++c) {
        ch_node[base + c] = n;
        ch_beg[base + c]  = b + CH * c;
        int l = min(CH, k - CH * c);
        ch_lm[base + c] = l | ((nc > 1) ? 0x10000 : 0);
    }
}

// ---------------- rotate + reduce via MFMA: one chunk (<=28 edges, one node)
// per block. out[49x128] = W[49xK] * X[Kx128], K = (slot,o) = 28*8 = 224
// (o=7 pad and empty-slot rows of W are zero, so they contribute nothing).
// A-frag: lane(m,quad) reads 16B at Ws[g*4+quad][wv*16+m] (k = quad*8+o).
// B-frag: lane(m,quad) reads 16B at X0p[es[g*4+quad]][nt*16+m]  - the exact
// o-minor layout gemm3 writes. 7 K-groups x 8 N-tiles = 56 MFMA per wave
// replaces 3136 scalar dot2 per thread (R2's 20% VALUBusy latency wall).
__global__ __launch_bounds__(256) void rotate_chunks_mfma(
    const unsigned short* __restrict__ X0p, // [NE,128,8] bf16 (already /RESCALE)
    const float* __restrict__ wig,          // [NE,49,29]
    const int* __restrict__ order,
    const int* __restrict__ chunk_cnt,
    const int* __restrict__ ch_node,
    const int* __restrict__ ch_beg,
    const int* __restrict__ ch_lm,
    float* __restrict__ out)                // [1600,49,128] (pre-zeroed)
{
    __shared__ unsigned short Ws[CH][64][8];   // [slot][row(49+pad15)][o(7+pad)] 28672 B
    __shared__ int es[CH];

    const int b = blockIdx.x;
    if (b >= chunk_cnt[0]) return;
    const int node = ch_node[b];
    const int beg  = ch_beg[b];
    const int lm   = ch_lm[b];
    const int len  = lm & 0xFFFF;
    const int multi = lm >> 16;

    const int t = threadIdx.x;
    const int wv = t >> 6, lane = t & 63;
    const int m = lane & 15, quad = lane >> 4;

    if (t < CH) es[t] = order[beg + ((t < len) ? t : 0)];

    // ---- stage wigner cols {0,2,6,11,16,21,26} -> Ws[slot][row][o] bf16.
    // Empty slots (>= len) staged as zeros => zero A contribution.
    const int slot8 = t >> 3;    // 0..31 (28..31 idle)
    const int lane8 = t & 7;
    if (slot8 < CH) {
        const int e = (slot8 < len) ? order[beg + slot8] : -1;
        const float* wsrc = wig + (size_t)e * (NSPH * NALLC);
#pragma unroll
        for (int j = 0; j < 49; ++j) {
            int idx = j * 8 + lane8;          // 0..391
            int i = idx >> 3, o = idx & 7;
            float v = 0.f;
            if (e >= 0 && o < 7) {
                int col = (o < 2) ? (2 * o) : (5 * o - 4);
                v = wsrc[i * NALLC + col];
            }
            Ws[slot8][i][o] = f_to_bf16(v);
        }
#pragma unroll
        for (int j = 0; j < 15; ++j)          // zero M-pad rows 49..63
            Ws[slot8][49 + j][lane8] = 0;
    }
    __syncthreads();

    // ---- MFMA: wave wv owns M-tile (rows wv*16..wv*16+15), all 8 N-tiles
    f32x4 acc[8] = {};
    for (int g = 0; g < 7; ++g) {
        const int e = es[g * 4 + quad];
        const unsigned short* xb = X0p + (size_t)e * 1024 + m * 8;
        bf16x8 aq = *(const bf16x8*)&Ws[g * 4 + quad][wv * 16 + m][0];
#pragma unroll
        for (int nt = 0; nt < 8; ++nt) {
            bf16x8 bq = *(const bf16x8*)(xb + nt * 128);
            acc[nt] = __builtin_amdgcn_mfma_f32_16x16x32_bf16(aq, bq, acc[nt], 0, 0, 0);
        }
    }

    // ---- C write: D row = wv*16 + quad*4 + reg (sph), col = nt*16 + m
    float* op = out + (size_t)node * (NSPH * CCH);
    const int r0 = wv * 16 + quad * 4;
    if (multi) {
#pragma unroll
        for (int nt = 0; nt < 8; ++nt) {
            int c = nt * 16 + m;
#pragma unroll
            for (int reg = 0; reg < 4; ++reg) {
                int sph = r0 + reg;
                if (sph < NSPH) atomicAdd(&op[sph * CCH + c], acc[nt][reg]);
            }
        }
    } else {
#pragma unroll
        for (int nt = 0; nt < 8; ++nt) {
            int c = nt * 16 + m;
#pragma unroll
            for (int reg = 0; reg < 4; ++reg) {
                int sph = r0 + reg;
                if (sph < NSPH) op[sph * CCH + c] = acc[nt][reg];
            }
        }
    }
}

extern "C" void kernel_launch(void* const* d_in, const int* in_sizes, int n_in,
                              void* d_out, int out_size, void* d_ws, size_t ws_size,
                              hipStream_t stream) {
    const int*   atomic_numbers = (const int*)d_in[0];
    const float* edge_distance  = (const float*)d_in[1];
    const int*   edge_index     = (const int*)d_in[2];
    const float* src_table      = (const float*)d_in[3];
    const float* tgt_table      = (const float*)d_in[4];
    const float* w1  = (const float*)d_in[5];
    const float* b1  = (const float*)d_in[6];
    const float* g1  = (const float*)d_in[7];
    const float* be1 = (const float*)d_in[8];
    const float* w2  = (const float*)d_in[9];
    const float* b2  = (const float*)d_in[10];
    const float* g2  = (const float*)d_in[11];
    const float* be2 = (const float*)d_in[12];
    const float* w3  = (const float*)d_in[13];
    const float* b3  = (const float*)d_in[14];
    // d_in[15] = to_m (fixed permutation, hard-coded)
    const float* wig = (const float*)d_in[16];

    char* ws = (char*)d_ws;
    // Non-overlapping layout, total ~82.6 MB (ws >= 90.1 MB proven previously)
    unsigned short* H1b = (unsigned short*)(ws);                 //  8.192 MB
    unsigned short* H2b = (unsigned short*)(ws + 8192000);       //  8.192 MB
    unsigned short* X0p = (unsigned short*)(ws + 16384000);      // 65.536 MB [NE,128,8]
    unsigned short* w1p = (unsigned short*)(ws + 81920000);      // 196608 B
    unsigned short* w2p = (unsigned short*)(ws + 82116608);      // 32768 B
    unsigned short* w3p = (unsigned short*)(ws + 82149376);      // 229376 B
    int* ints      = (int*)(ws + 82378752);
    int* cnt       = ints;                   // [1600]
    int* chunk_cnt = cnt + NNODES;           // [1]
    int* offs      = chunk_cnt + 1;          // [1601]
    int* cur       = offs + NNODES + 1;      // [1600]
    int* order     = cur + NNODES;           // [32000]
    int* ch_node   = order + NE;             // [MAXCH]
    int* ch_beg    = ch_node + MAXCH;        // [MAXCH]
    int* ch_lm     = ch_beg + MAXCH;         // [MAXCH]

    // zero cnt + chunk_cnt (adjacent), and the output (multi-chunk atomics + empty nodes)
    hipMemsetAsync(cnt, 0, (NNODES + 1) * sizeof(int), stream);
    hipMemsetAsync(d_out, 0, (size_t)out_size * sizeof(float), stream);

    // bucket + chunk build
    hist_kernel<<<(NE + 255) / 256, 256, 0, stream>>>(edge_index, cnt);
    scan_kernel<<<1, 256, 0, stream>>>(cnt, offs, cur);
    scatter_kernel<<<(NE + 255) / 256, 256, 0, stream>>>(edge_index, cur, order);
    build_chunks<<<(NNODES + 255) / 256, 256, 0, stream>>>(
        offs, chunk_cnt, ch_node, ch_beg, ch_lm);

    // weights prepack + MLP (bf16 MFMA)
    prepack_w<<<(229376 + 255) / 256, 256, 0, stream>>>(w1, w2, w3, w1p, w2p, w3p);
    gemm1_ln_mfma<<<NE / 64, 256, 0, stream>>>(
        edge_distance, edge_index, atomic_numbers, src_table, tgt_table,
        w1p, b1, g1, be1, H1b);
    gemm2_ln_mfma<<<NE / 64, 256, 0, stream>>>(H1b, w2p, b2, g2, be2, H2b);
    gemm3_mfma<<<NE / 16, 256, 0, stream>>>(H2b, w3p, b3, X0p);

    // rotate + reduce (MFMA)
    rotate_chunks_mfma<<<MAXCH, 256, 0, stream>>>(
        X0p, wig, order, chunk_cnt, ch_node, ch_beg, ch_lm, (float*)d_out);
}